// Round 2
// baseline (3070.496 us; speedup 1.0000x reference)
//
#include <hip/hip_runtime.h>

#define CDIM 64

// --- GEMM: per-thread node row, weights read via wave-uniform (scalar) loads ---
__device__ __forceinline__ void gemm_row(const float xr[CDIM], const float* __restrict__ w,
                                         const float* __restrict__ bias, float* __restrict__ o) {
    const float4* w4 = (const float4*)w;
    for (int j4 = 0; j4 < CDIM / 4; ++j4) {
        float4 acc;
        if (bias != nullptr) {
            acc = ((const float4*)bias)[j4];
        } else {
            acc.x = acc.y = acc.z = acc.w = 0.0f;
        }
#pragma unroll
        for (int k = 0; k < CDIM; ++k) {
            float4 wv = w4[k * (CDIM / 4) + j4];  // uniform address -> scalar loads
            float xk = xr[k];
            acc.x += xk * wv.x;
            acc.y += xk * wv.y;
            acc.z += xk * wv.z;
            acc.w += xk * wv.w;
        }
        ((float4*)o)[j4] = acc;
    }
}

__global__ __launch_bounds__(256) void k_gemm3(const float* __restrict__ x,
                                               const float* __restrict__ w0,
                                               const float* __restrict__ w1,
                                               const float* __restrict__ root,
                                               const float* __restrict__ bias,
                                               float* __restrict__ h0,
                                               float* __restrict__ h1,
                                               float* __restrict__ lin,
                                               int n_nodes) {
    int n = blockIdx.x * 256 + threadIdx.x;
    if (n >= n_nodes) return;
    float xr[CDIM];
    const float4* xv = (const float4*)(x + (size_t)n * CDIM);
#pragma unroll
    for (int i = 0; i < CDIM / 4; ++i) {
        float4 v = xv[i];
        xr[4 * i + 0] = v.x;
        xr[4 * i + 1] = v.y;
        xr[4 * i + 2] = v.z;
        xr[4 * i + 3] = v.w;
    }
    gemm_row(xr, w0, nullptr, h0 + (size_t)n * CDIM);
    gemm_row(xr, w1, nullptr, h1 + (size_t)n * CDIM);
    gemm_row(xr, root, bias, lin + (size_t)n * CDIM);
}

// --- zero-fill (graph-capture-safe scratch init) ---
__global__ __launch_bounds__(256) void k_zero(float* __restrict__ p, size_t n) {
    size_t t = (size_t)blockIdx.x * 256 + threadIdx.x;
    size_t stride = (size_t)gridDim.x * 256;
    for (size_t i = t; i < n; i += stride) p[i] = 0.0f;
}

// --- degree: one thread per edge (indices are int32 per harness ABI) ---
__global__ __launch_bounds__(256) void k_deg(const int* __restrict__ dst,
                                             float* __restrict__ deg, int n_edges) {
    int e = blockIdx.x * 256 + threadIdx.x;
    if (e >= n_edges) return;
    atomicAdd(&deg[dst[e]], 1.0f);
}

// --- edge gather + scatter-add: 16 threads per edge, float4 per thread ---
__global__ __launch_bounds__(256) void k_edge(const float* __restrict__ h0,
                                              const float* __restrict__ h1,
                                              const int* __restrict__ src,
                                              const int* __restrict__ dst,
                                              const float* __restrict__ u,
                                              float* __restrict__ agg, int n_edges) {
    int t = blockIdx.x * 256 + threadIdx.x;
    int e = t >> 4;
    if (e >= n_edges) return;
    int c = (t & 15) * 4;
    int s = src[e];
    int d = dst[e];
    float ue = u[e];
    float w1v = ue;
    float w0v = 1.0f - ue;
    float4 a = *(const float4*)(h0 + (size_t)s * CDIM + c);
    float4 b = *(const float4*)(h1 + (size_t)s * CDIM + c);
    float4 m;
    m.x = w0v * a.x + w1v * b.x;
    m.y = w0v * a.y + w1v * b.y;
    m.z = w0v * a.z + w1v * b.z;
    m.w = w0v * a.w + w1v * b.w;
    float* ap = agg + (size_t)d * CDIM + c;
    atomicAdd(ap + 0, m.x);
    atomicAdd(ap + 1, m.y);
    atomicAdd(ap + 2, m.z);
    atomicAdd(ap + 3, m.w);
}

// --- finalize: out = agg / max(deg,1) + lin (in-place safe when lin==out) ---
__global__ __launch_bounds__(256) void k_final(const float* __restrict__ agg,
                                               const float* __restrict__ deg,
                                               const float* __restrict__ lin,
                                               float* __restrict__ out, int n_nodes) {
    int t = blockIdx.x * 256 + threadIdx.x;
    if (t >= n_nodes * (CDIM / 4)) return;
    int n = t >> 4;
    float d = fmaxf(deg[n], 1.0f);
    float4 a = ((const float4*)agg)[t];
    float4 l = ((const float4*)lin)[t];
    float4 o;
    o.x = a.x / d + l.x;
    o.y = a.y / d + l.y;
    o.z = a.z / d + l.z;
    o.w = a.w / d + l.w;
    ((float4*)out)[t] = o;
}

extern "C" void kernel_launch(void* const* d_in, const int* in_sizes, int n_in,
                              void* d_out, int out_size, void* d_ws, size_t ws_size,
                              hipStream_t stream) {
    const float* x = (const float*)d_in[0];
    const int* edge_index = (const int*)d_in[1];   // harness delivers integer inputs as int32
    const float* edge_attr = (const float*)d_in[2];
    const float* w1 = (const float*)d_in[3];
    const float* root1 = (const float*)d_in[4];
    const float* b1 = (const float*)d_in[5];
    const float* w2 = (const float*)d_in[6];
    const float* root2 = (const float*)d_in[7];
    const float* b2 = (const float*)d_in[8];

    int n_nodes = in_sizes[0] / CDIM;
    int n_edges = in_sizes[2];
    const int* src = edge_index;
    const int* dst = edge_index + n_edges;

    size_t F = (size_t)n_nodes * CDIM;
    float* h0 = (float*)d_ws;
    float* h1 = h0 + F;
    float* lin = h1 + F;
    float* agg = lin + F;
    float* deg = agg + F;   // deg is adjacent to agg -> can zero together
    float* out = (float*)d_out;

    int gN = (n_nodes + 255) / 256;          // node-per-thread grids
    int gE = (n_edges + 255) / 256;          // edge-per-thread grids
    int gE16 = (int)(((size_t)n_edges * 16 + 255) / 256);   // 16 threads/edge
    int gF4 = ((n_nodes * (CDIM / 4)) + 255) / 256;

    // ---- layer 1 ----
    // zero agg+deg in one pass (contiguous), then degree counts
    k_zero<<<2048, 256, 0, stream>>>(agg, F + (size_t)n_nodes);
    k_deg<<<gE, 256, 0, stream>>>(dst, deg, n_edges);
    k_gemm3<<<gN, 256, 0, stream>>>(x, w1, w1 + CDIM * CDIM, root1, b1, h0, h1, lin, n_nodes);
    k_edge<<<gE16, 256, 0, stream>>>(h0, h1, src, dst, edge_attr, agg, n_edges);
    k_final<<<gF4, 256, 0, stream>>>(agg, deg, lin, lin, n_nodes);  // lin now holds layer-1 output

    // ---- layer 2 ----
    k_zero<<<2048, 256, 0, stream>>>(agg, F);
    k_gemm3<<<gN, 256, 0, stream>>>(lin, w2, w2 + CDIM * CDIM, root2, b2, h0, h1, out, n_nodes);
    k_edge<<<gE16, 256, 0, stream>>>(h0, h1, src, dst, edge_attr, agg, n_edges);
    k_final<<<gF4, 256, 0, stream>>>(agg, deg, out, out, n_nodes);
}

// Round 3
// 810.058 us; speedup vs baseline: 3.7905x; 3.7905x over previous
//
#include <hip/hip_runtime.h>

#define CDIM 64

// --- GEMM: per-thread node row, weights read via wave-uniform (scalar) loads ---
__device__ __forceinline__ void gemm_row(const float xr[CDIM], const float* __restrict__ w,
                                         const float* __restrict__ bias, float* __restrict__ o) {
    const float4* w4 = (const float4*)w;
    for (int j4 = 0; j4 < CDIM / 4; ++j4) {
        float4 acc;
        if (bias != nullptr) {
            acc = ((const float4*)bias)[j4];
        } else {
            acc.x = acc.y = acc.z = acc.w = 0.0f;
        }
#pragma unroll
        for (int k = 0; k < CDIM; ++k) {
            float4 wv = w4[k * (CDIM / 4) + j4];
            float xk = xr[k];
            acc.x += xk * wv.x;
            acc.y += xk * wv.y;
            acc.z += xk * wv.z;
            acc.w += xk * wv.w;
        }
        ((float4*)o)[j4] = acc;
    }
}

__global__ __launch_bounds__(256) void k_gemm3(const float* __restrict__ x,
                                               const float* __restrict__ w0,
                                               const float* __restrict__ w1,
                                               const float* __restrict__ root,
                                               const float* __restrict__ bias,
                                               float* __restrict__ h0,
                                               float* __restrict__ h1,
                                               float* __restrict__ lin,
                                               int n_nodes) {
    int n = blockIdx.x * 256 + threadIdx.x;
    if (n >= n_nodes) return;
    float xr[CDIM];
    const float4* xv = (const float4*)(x + (size_t)n * CDIM);
#pragma unroll
    for (int i = 0; i < CDIM / 4; ++i) {
        float4 v = xv[i];
        xr[4 * i + 0] = v.x;
        xr[4 * i + 1] = v.y;
        xr[4 * i + 2] = v.z;
        xr[4 * i + 3] = v.w;
    }
    gemm_row(xr, w0, nullptr, h0 + (size_t)n * CDIM);
    gemm_row(xr, w1, nullptr, h1 + (size_t)n * CDIM);
    gemm_row(xr, root, bias, lin + (size_t)n * CDIM);
}

// --- zero-fill ---
__global__ __launch_bounds__(256) void k_zero(int* __restrict__ p, size_t n) {
    size_t t = (size_t)blockIdx.x * 256 + threadIdx.x;
    size_t stride = (size_t)gridDim.x * 256;
    for (size_t i = t; i < n; i += stride) p[i] = 0;
}

// --- histogram of dst ---
__global__ __launch_bounds__(256) void k_hist(const int* __restrict__ dst,
                                              int* __restrict__ cnt, int n_edges) {
    int e = blockIdx.x * 256 + threadIdx.x;
    if (e >= n_edges) return;
    atomicAdd(&cnt[dst[e]], 1);
}

// --- single-block exclusive scan over cnt -> row_start[0..n], cursor copy ---
__global__ __launch_bounds__(1024) void k_scan(const int* __restrict__ cnt,
                                               int* __restrict__ row_start,
                                               int* __restrict__ cursor, int n) {
    __shared__ int buf[1024];
    __shared__ int carry_s;
    int tid = threadIdx.x;
    if (tid == 0) carry_s = 0;
    __syncthreads();
    for (int base = 0; base < n; base += 1024) {
        int idx = base + tid;
        int v = (idx < n) ? cnt[idx] : 0;
        buf[tid] = v;
        __syncthreads();
        for (int off = 1; off < 1024; off <<= 1) {
            int t = (tid >= off) ? buf[tid - off] : 0;
            __syncthreads();
            buf[tid] += t;
            __syncthreads();
        }
        int incl = buf[tid];
        int c = carry_s;
        int excl = incl - v + c;
        if (idx < n) {
            row_start[idx] = excl;
            cursor[idx] = excl;
        }
        __syncthreads();
        if (tid == 1023) carry_s = c + buf[1023];
        __syncthreads();
    }
    if (tid == 0) row_start[n] = carry_s;
}

// --- scatter edges into dst-sorted order ---
__global__ __launch_bounds__(256) void k_scatter(const int* __restrict__ src,
                                                 const int* __restrict__ dst,
                                                 const float* __restrict__ u,
                                                 int* __restrict__ cursor,
                                                 int* __restrict__ es,
                                                 float* __restrict__ eu, int n_edges) {
    int e = blockIdx.x * 256 + threadIdx.x;
    if (e >= n_edges) return;
    int d = dst[e];
    int p = atomicAdd(&cursor[d], 1);
    es[p] = src[e];
    eu[p] = u[e];
}

// --- aggregate: one wave per node, lane = channel; fused mean + lin add ---
__global__ __launch_bounds__(256) void k_agg(const float* __restrict__ h0,
                                             const float* __restrict__ h1,
                                             const int* __restrict__ es,
                                             const float* __restrict__ eu,
                                             const int* __restrict__ row_start,
                                             const float* __restrict__ lin,
                                             float* __restrict__ out, int n_nodes) {
    int wave = threadIdx.x >> 6;
    int lane = threadIdx.x & 63;
    int n = blockIdx.x * 4 + wave;
    if (n >= n_nodes) return;
    int start = row_start[n];
    int end = row_start[n + 1];
    float acc = 0.0f;
    int j = start;
    for (; j + 4 <= end; j += 4) {
        int s0 = es[j + 0], s1 = es[j + 1], s2 = es[j + 2], s3 = es[j + 3];
        float u0 = eu[j + 0], u1 = eu[j + 1], u2 = eu[j + 2], u3 = eu[j + 3];
        float a0 = h0[(size_t)s0 * CDIM + lane], b0 = h1[(size_t)s0 * CDIM + lane];
        float a1 = h0[(size_t)s1 * CDIM + lane], b1 = h1[(size_t)s1 * CDIM + lane];
        float a2 = h0[(size_t)s2 * CDIM + lane], b2 = h1[(size_t)s2 * CDIM + lane];
        float a3 = h0[(size_t)s3 * CDIM + lane], b3 = h1[(size_t)s3 * CDIM + lane];
        acc += a0 + u0 * (b0 - a0);   // (1-u)a + u b
        acc += a1 + u1 * (b1 - a1);
        acc += a2 + u2 * (b2 - a2);
        acc += a3 + u3 * (b3 - a3);
    }
    for (; j < end; ++j) {
        int s = es[j];
        float uu = eu[j];
        float a = h0[(size_t)s * CDIM + lane], b = h1[(size_t)s * CDIM + lane];
        acc += a + uu * (b - a);
    }
    float d = fmaxf((float)(end - start), 1.0f);
    size_t o = (size_t)n * CDIM + lane;
    out[o] = acc / d + lin[o];
}

extern "C" void kernel_launch(void* const* d_in, const int* in_sizes, int n_in,
                              void* d_out, int out_size, void* d_ws, size_t ws_size,
                              hipStream_t stream) {
    const float* x = (const float*)d_in[0];
    const int* edge_index = (const int*)d_in[1];
    const float* edge_attr = (const float*)d_in[2];
    const float* w1 = (const float*)d_in[3];
    const float* root1 = (const float*)d_in[4];
    const float* b1 = (const float*)d_in[5];
    const float* w2 = (const float*)d_in[6];
    const float* root2 = (const float*)d_in[7];
    const float* b2 = (const float*)d_in[8];

    int n_nodes = in_sizes[0] / CDIM;
    int n_edges = in_sizes[2];
    const int* src = edge_index;
    const int* dst = edge_index + n_edges;

    size_t F = (size_t)n_nodes * CDIM;
    float* h0 = (float*)d_ws;
    float* h1 = h0 + F;
    float* lin = h1 + F;
    float* eu = lin + F;
    int* es = (int*)(eu + n_edges);
    int* cnt = es + n_edges;
    int* row_start = cnt + n_nodes;        // n_nodes+1 entries
    int* cursor = row_start + n_nodes + 1;
    float* out = (float*)d_out;

    int gN = (n_nodes + 255) / 256;
    int gE = (n_edges + 255) / 256;
    int gA = (n_nodes + 3) / 4;   // 4 waves/block, 1 node/wave

    // ---- build dst-CSR (shared by both layers) ----
    k_zero<<<256, 256, 0, stream>>>(cnt, (size_t)n_nodes);
    k_hist<<<gE, 256, 0, stream>>>(dst, cnt, n_edges);
    k_scan<<<1, 1024, 0, stream>>>(cnt, row_start, cursor, n_nodes);
    k_scatter<<<gE, 256, 0, stream>>>(src, dst, edge_attr, cursor, es, eu, n_edges);

    // ---- layer 1 ----
    k_gemm3<<<gN, 256, 0, stream>>>(x, w1, w1 + CDIM * CDIM, root1, b1, h0, h1, lin, n_nodes);
    k_agg<<<gA, 256, 0, stream>>>(h0, h1, es, eu, row_start, lin, lin, n_nodes);

    // ---- layer 2 ----
    k_gemm3<<<gN, 256, 0, stream>>>(lin, w2, w2 + CDIM * CDIM, root2, b2, h0, h1, out, n_nodes);
    k_agg<<<gA, 256, 0, stream>>>(h0, h1, es, eu, row_start, out, out, n_nodes);
}

// Round 4
// 696.907 us; speedup vs baseline: 4.4059x; 1.1624x over previous
//
#include <hip/hip_runtime.h>

#define CDIM 64

// --- GEMM: per-thread node row, weights read via wave-uniform (scalar) loads ---
__device__ __forceinline__ void gemm_row(const float xr[CDIM], const float* __restrict__ w,
                                         const float* __restrict__ bias, float* __restrict__ o) {
    const float4* w4 = (const float4*)w;
    for (int j4 = 0; j4 < CDIM / 4; ++j4) {
        float4 acc;
        if (bias != nullptr) {
            acc = ((const float4*)bias)[j4];
        } else {
            acc.x = acc.y = acc.z = acc.w = 0.0f;
        }
#pragma unroll
        for (int k = 0; k < CDIM; ++k) {
            float4 wv = w4[k * (CDIM / 4) + j4];
            float xk = xr[k];
            acc.x += xk * wv.x;
            acc.y += xk * wv.y;
            acc.z += xk * wv.z;
            acc.w += xk * wv.w;
        }
        ((float4*)o)[j4] = acc;
    }
}

__global__ __launch_bounds__(256) void k_gemm3(const float* __restrict__ x,
                                               const float* __restrict__ w0,
                                               const float* __restrict__ w1,
                                               const float* __restrict__ root,
                                               const float* __restrict__ bias,
                                               float* __restrict__ h0,
                                               float* __restrict__ h1,
                                               float* __restrict__ lin,
                                               int n_nodes) {
    int n = blockIdx.x * 256 + threadIdx.x;
    if (n >= n_nodes) return;
    float xr[CDIM];
    const float4* xv = (const float4*)(x + (size_t)n * CDIM);
#pragma unroll
    for (int i = 0; i < CDIM / 4; ++i) {
        float4 v = xv[i];
        xr[4 * i + 0] = v.x;
        xr[4 * i + 1] = v.y;
        xr[4 * i + 2] = v.z;
        xr[4 * i + 3] = v.w;
    }
    gemm_row(xr, w0, nullptr, h0 + (size_t)n * CDIM);
    gemm_row(xr, w1, nullptr, h1 + (size_t)n * CDIM);
    gemm_row(xr, root, bias, lin + (size_t)n * CDIM);
}

// --- zero-fill ---
__global__ __launch_bounds__(256) void k_zero(int* __restrict__ p, size_t n) {
    size_t t = (size_t)blockIdx.x * 256 + threadIdx.x;
    size_t stride = (size_t)gridDim.x * 256;
    for (size_t i = t; i < n; i += stride) p[i] = 0;
}

// --- histogram of dst ---
__global__ __launch_bounds__(256) void k_hist(const int* __restrict__ dst,
                                              int* __restrict__ cnt, int n_edges) {
    int e = blockIdx.x * 256 + threadIdx.x;
    if (e >= n_edges) return;
    atomicAdd(&cnt[dst[e]], 1);
}

// ===== two-level scan: 1024 elements per block (256 threads x 4) =====
#define SCAN_B 1024

// pass 1: per-block sums
__global__ __launch_bounds__(256) void k_scan1(const int* __restrict__ cnt,
                                               int* __restrict__ blk_sum, int n) {
    __shared__ int sm[256];
    int tid = threadIdx.x;
    int base = blockIdx.x * SCAN_B + tid * 4;
    int s = 0;
#pragma unroll
    for (int i = 0; i < 4; ++i) s += (base + i < n) ? cnt[base + i] : 0;
    sm[tid] = s;
    __syncthreads();
    for (int off = 128; off > 0; off >>= 1) {
        if (tid < off) sm[tid] += sm[tid + off];
        __syncthreads();
    }
    if (tid == 0) blk_sum[blockIdx.x] = sm[0];
}

// pass 2: exclusive scan of block sums (nb <= 256), writes total to row_start[n]
__global__ __launch_bounds__(256) void k_scan2(int* __restrict__ blk_sum,
                                               int* __restrict__ row_start,
                                               int nb, int n) {
    __shared__ int sm[256];
    int tid = threadIdx.x;
    int v = (tid < nb) ? blk_sum[tid] : 0;
    sm[tid] = v;
    __syncthreads();
    for (int off = 1; off < 256; off <<= 1) {
        int t = (tid >= off) ? sm[tid - off] : 0;
        __syncthreads();
        sm[tid] += t;
        __syncthreads();
    }
    if (tid < nb) blk_sum[tid] = sm[tid] - v;  // exclusive
    if (tid == 255) row_start[n] = sm[255];    // grand total
}

// pass 3: per-block exclusive scan + block offset -> row_start, cursor
__global__ __launch_bounds__(256) void k_scan3(const int* __restrict__ cnt,
                                               const int* __restrict__ blk_off,
                                               int* __restrict__ row_start,
                                               int* __restrict__ cursor, int n) {
    __shared__ int sm[256];
    int tid = threadIdx.x;
    int base = blockIdx.x * SCAN_B + tid * 4;
    int v[4];
    int s = 0;
#pragma unroll
    for (int i = 0; i < 4; ++i) {
        v[i] = (base + i < n) ? cnt[base + i] : 0;
        s += v[i];
    }
    sm[tid] = s;
    __syncthreads();
    for (int off = 1; off < 256; off <<= 1) {
        int t = (tid >= off) ? sm[tid - off] : 0;
        __syncthreads();
        sm[tid] += t;
        __syncthreads();
    }
    int run = sm[tid] - s + blk_off[blockIdx.x];  // exclusive prefix for this thread
#pragma unroll
    for (int i = 0; i < 4; ++i) {
        if (base + i < n) {
            row_start[base + i] = run;
            cursor[base + i] = run;
        }
        run += v[i];
    }
}

// --- scatter edges into dst-sorted order ---
__global__ __launch_bounds__(256) void k_scatter(const int* __restrict__ src,
                                                 const int* __restrict__ dst,
                                                 const float* __restrict__ u,
                                                 int* __restrict__ cursor,
                                                 int* __restrict__ es,
                                                 float* __restrict__ eu, int n_edges) {
    int e = blockIdx.x * 256 + threadIdx.x;
    if (e >= n_edges) return;
    int d = dst[e];
    int p = atomicAdd(&cursor[d], 1);
    es[p] = src[e];
    eu[p] = u[e];
}

// --- aggregate: one wave per node, lane = channel; fused mean + lin add ---
__global__ __launch_bounds__(256) void k_agg(const float* __restrict__ h0,
                                             const float* __restrict__ h1,
                                             const int* __restrict__ es,
                                             const float* __restrict__ eu,
                                             const int* __restrict__ row_start,
                                             const float* __restrict__ lin,
                                             float* __restrict__ out, int n_nodes) {
    int wave = threadIdx.x >> 6;
    int lane = threadIdx.x & 63;
    int n = blockIdx.x * 4 + wave;
    if (n >= n_nodes) return;
    int start = row_start[n];
    int end = row_start[n + 1];
    float acc = 0.0f;
    int j = start;
    for (; j + 4 <= end; j += 4) {
        int s0 = es[j + 0], s1 = es[j + 1], s2 = es[j + 2], s3 = es[j + 3];
        float u0 = eu[j + 0], u1 = eu[j + 1], u2 = eu[j + 2], u3 = eu[j + 3];
        float a0 = h0[(size_t)s0 * CDIM + lane], b0 = h1[(size_t)s0 * CDIM + lane];
        float a1 = h0[(size_t)s1 * CDIM + lane], b1 = h1[(size_t)s1 * CDIM + lane];
        float a2 = h0[(size_t)s2 * CDIM + lane], b2 = h1[(size_t)s2 * CDIM + lane];
        float a3 = h0[(size_t)s3 * CDIM + lane], b3 = h1[(size_t)s3 * CDIM + lane];
        acc += a0 + u0 * (b0 - a0);   // (1-u)a + u b
        acc += a1 + u1 * (b1 - a1);
        acc += a2 + u2 * (b2 - a2);
        acc += a3 + u3 * (b3 - a3);
    }
    for (; j < end; ++j) {
        int s = es[j];
        float uu = eu[j];
        float a = h0[(size_t)s * CDIM + lane], b = h1[(size_t)s * CDIM + lane];
        acc += a + uu * (b - a);
    }
    float d = fmaxf((float)(end - start), 1.0f);
    size_t o = (size_t)n * CDIM + lane;
    out[o] = acc / d + lin[o];
}

extern "C" void kernel_launch(void* const* d_in, const int* in_sizes, int n_in,
                              void* d_out, int out_size, void* d_ws, size_t ws_size,
                              hipStream_t stream) {
    const float* x = (const float*)d_in[0];
    const int* edge_index = (const int*)d_in[1];
    const float* edge_attr = (const float*)d_in[2];
    const float* w1 = (const float*)d_in[3];
    const float* root1 = (const float*)d_in[4];
    const float* b1 = (const float*)d_in[5];
    const float* w2 = (const float*)d_in[6];
    const float* root2 = (const float*)d_in[7];
    const float* b2 = (const float*)d_in[8];

    int n_nodes = in_sizes[0] / CDIM;
    int n_edges = in_sizes[2];
    const int* src = edge_index;
    const int* dst = edge_index + n_edges;

    size_t F = (size_t)n_nodes * CDIM;
    float* h0 = (float*)d_ws;
    float* h1 = h0 + F;
    float* lin = h1 + F;
    float* eu = lin + F;
    int* es = (int*)(eu + n_edges);
    int* cnt = es + n_edges;
    int* row_start = cnt + n_nodes;        // n_nodes+1 entries
    int* cursor = row_start + n_nodes + 1;
    int* blk_sum = cursor + n_nodes;       // ceil(n/1024) entries
    float* out = (float*)d_out;

    int gN = (n_nodes + 255) / 256;
    int gE = (n_edges + 255) / 256;
    int gA = (n_nodes + 3) / 4;            // 4 waves/block, 1 node/wave
    int nb = (n_nodes + SCAN_B - 1) / SCAN_B;  // 98 blocks for 100k — fits k_scan2's 256

    // ---- build dst-CSR (shared by both layers) ----
    k_zero<<<256, 256, 0, stream>>>(cnt, (size_t)n_nodes);
    k_hist<<<gE, 256, 0, stream>>>(dst, cnt, n_edges);
    k_scan1<<<nb, 256, 0, stream>>>(cnt, blk_sum, n_nodes);
    k_scan2<<<1, 256, 0, stream>>>(blk_sum, row_start, nb, n_nodes);
    k_scan3<<<nb, 256, 0, stream>>>(cnt, blk_sum, row_start, cursor, n_nodes);
    k_scatter<<<gE, 256, 0, stream>>>(src, dst, edge_attr, cursor, es, eu, n_edges);

    // ---- layer 1 ----
    k_gemm3<<<gN, 256, 0, stream>>>(x, w1, w1 + CDIM * CDIM, root1, b1, h0, h1, lin, n_nodes);
    k_agg<<<gA, 256, 0, stream>>>(h0, h1, es, eu, row_start, lin, lin, n_nodes);

    // ---- layer 2 ----
    k_gemm3<<<gN, 256, 0, stream>>>(lin, w2, w2 + CDIM * CDIM, root2, b2, h0, h1, out, n_nodes);
    k_agg<<<gA, 256, 0, stream>>>(h0, h1, es, eu, row_start, out, out, n_nodes);
}

// Round 5
// 611.060 us; speedup vs baseline: 5.0249x; 1.1405x over previous
//
#include <hip/hip_runtime.h>

#define CDIM 64

// round-to-nearest-even bf16 pack: lo -> bits[15:0], hi -> bits[31:16]
__device__ __forceinline__ unsigned bfpack(float lo, float hi) {
    unsigned a = __float_as_uint(lo);
    a = (a + 0x7fffu + ((a >> 16) & 1u)) >> 16;
    unsigned b = __float_as_uint(hi);
    b = (b + 0x7fffu + ((b >> 16) & 1u)) & 0xffff0000u;
    return a | b;
}

// --- fused 3-GEMM: per-thread node row; w0/w1 outputs packed bf16x2, root+bias fp32 ---
__global__ __launch_bounds__(256) void k_gemm3(const float* __restrict__ x,
                                               const float* __restrict__ w0,
                                               const float* __restrict__ w1,
                                               const float* __restrict__ root,
                                               const float* __restrict__ bias,
                                               unsigned* __restrict__ h01,
                                               float* __restrict__ lin,
                                               int n_nodes) {
    int n = blockIdx.x * 256 + threadIdx.x;
    if (n >= n_nodes) return;
    float xr[CDIM];
    const float4* xv = (const float4*)(x + (size_t)n * CDIM);
#pragma unroll
    for (int i = 0; i < CDIM / 4; ++i) {
        float4 v = xv[i];
        xr[4 * i + 0] = v.x;
        xr[4 * i + 1] = v.y;
        xr[4 * i + 2] = v.z;
        xr[4 * i + 3] = v.w;
    }
    const float4* w04 = (const float4*)w0;
    const float4* w14 = (const float4*)w1;
    const float4* wr4 = (const float4*)root;
    const float4* b4 = (const float4*)bias;
    for (int j4 = 0; j4 < CDIM / 4; ++j4) {
        float4 a0 = {0.f, 0.f, 0.f, 0.f};
        float4 a1 = {0.f, 0.f, 0.f, 0.f};
        float4 al = b4[j4];
#pragma unroll
        for (int k = 0; k < CDIM; ++k) {
            float xk = xr[k];
            float4 v0 = w04[k * (CDIM / 4) + j4];   // wave-uniform -> scalar loads
            float4 v1 = w14[k * (CDIM / 4) + j4];
            float4 vr = wr4[k * (CDIM / 4) + j4];
            a0.x += xk * v0.x; a0.y += xk * v0.y; a0.z += xk * v0.z; a0.w += xk * v0.w;
            a1.x += xk * v1.x; a1.y += xk * v1.y; a1.z += xk * v1.z; a1.w += xk * v1.w;
            al.x += xk * vr.x; al.y += xk * vr.y; al.z += xk * vr.z; al.w += xk * vr.w;
        }
        uint4 p;
        p.x = bfpack(a0.x, a1.x);
        p.y = bfpack(a0.y, a1.y);
        p.z = bfpack(a0.z, a1.z);
        p.w = bfpack(a0.w, a1.w);
        ((uint4*)(h01 + (size_t)n * CDIM))[j4] = p;
        ((float4*)(lin + (size_t)n * CDIM))[j4] = al;
    }
}

// --- zero-fill ---
__global__ __launch_bounds__(256) void k_zero(int* __restrict__ p, size_t n) {
    size_t t = (size_t)blockIdx.x * 256 + threadIdx.x;
    size_t stride = (size_t)gridDim.x * 256;
    for (size_t i = t; i < n; i += stride) p[i] = 0;
}

// --- histogram of dst ---
__global__ __launch_bounds__(256) void k_hist(const int* __restrict__ dst,
                                              int* __restrict__ cnt, int n_edges) {
    int e = blockIdx.x * 256 + threadIdx.x;
    if (e >= n_edges) return;
    atomicAdd(&cnt[dst[e]], 1);
}

// ===== two-level scan: 1024 elements per block =====
#define SCAN_B 1024

__global__ __launch_bounds__(256) void k_scan1(const int* __restrict__ cnt,
                                               int* __restrict__ blk_sum, int n) {
    __shared__ int sm[256];
    int tid = threadIdx.x;
    int base = blockIdx.x * SCAN_B + tid * 4;
    int s = 0;
#pragma unroll
    for (int i = 0; i < 4; ++i) s += (base + i < n) ? cnt[base + i] : 0;
    sm[tid] = s;
    __syncthreads();
    for (int off = 128; off > 0; off >>= 1) {
        if (tid < off) sm[tid] += sm[tid + off];
        __syncthreads();
    }
    if (tid == 0) blk_sum[blockIdx.x] = sm[0];
}

__global__ __launch_bounds__(256) void k_scan2(int* __restrict__ blk_sum,
                                               int* __restrict__ row_start,
                                               int nb, int n) {
    __shared__ int sm[256];
    int tid = threadIdx.x;
    int v = (tid < nb) ? blk_sum[tid] : 0;
    sm[tid] = v;
    __syncthreads();
    for (int off = 1; off < 256; off <<= 1) {
        int t = (tid >= off) ? sm[tid - off] : 0;
        __syncthreads();
        sm[tid] += t;
        __syncthreads();
    }
    if (tid < nb) blk_sum[tid] = sm[tid] - v;  // exclusive
    if (tid == 255) row_start[n] = sm[255];    // grand total
}

__global__ __launch_bounds__(256) void k_scan3(const int* __restrict__ cnt,
                                               const int* __restrict__ blk_off,
                                               int* __restrict__ row_start,
                                               int* __restrict__ cursor, int n) {
    __shared__ int sm[256];
    int tid = threadIdx.x;
    int base = blockIdx.x * SCAN_B + tid * 4;
    int v[4];
    int s = 0;
#pragma unroll
    for (int i = 0; i < 4; ++i) {
        v[i] = (base + i < n) ? cnt[base + i] : 0;
        s += v[i];
    }
    sm[tid] = s;
    __syncthreads();
    for (int off = 1; off < 256; off <<= 1) {
        int t = (tid >= off) ? sm[tid - off] : 0;
        __syncthreads();
        sm[tid] += t;
        __syncthreads();
    }
    int run = sm[tid] - s + blk_off[blockIdx.x];
#pragma unroll
    for (int i = 0; i < 4; ++i) {
        if (base + i < n) {
            row_start[base + i] = run;
            cursor[base + i] = run;
        }
        run += v[i];
    }
}

// --- scatter edges into dst-sorted order; packed (src, u) 8B payload ---
__global__ __launch_bounds__(256) void k_scatter(const int* __restrict__ src,
                                                 const int* __restrict__ dst,
                                                 const float* __restrict__ u,
                                                 int* __restrict__ cursor,
                                                 int2* __restrict__ em, int n_edges) {
    int e = blockIdx.x * 256 + threadIdx.x;
    if (e >= n_edges) return;
    int d = dst[e];
    int p = atomicAdd(&cursor[d], 1);
    em[p] = make_int2(src[e], __float_as_int(u[e]));
}

// --- aggregate: one wave per node, lane = channel; packed bf16 h01, fused epilogue ---
__global__ __launch_bounds__(256) void k_agg(const unsigned* __restrict__ h01,
                                             const int2* __restrict__ em,
                                             const int* __restrict__ row_start,
                                             const float* __restrict__ lin,
                                             float* __restrict__ out, int n_nodes) {
    int wave = threadIdx.x >> 6;
    int lane = threadIdx.x & 63;
    int n = blockIdx.x * 4 + wave;
    if (n >= n_nodes) return;
    int start = row_start[n];
    int end = row_start[n + 1];
    float acc = 0.0f;
    int j = start;
    for (; j + 4 <= end; j += 4) {
        int2 e0 = em[j + 0], e1 = em[j + 1], e2 = em[j + 2], e3 = em[j + 3];
        unsigned v0 = h01[(size_t)e0.x * CDIM + lane];
        unsigned v1 = h01[(size_t)e1.x * CDIM + lane];
        unsigned v2 = h01[(size_t)e2.x * CDIM + lane];
        unsigned v3 = h01[(size_t)e3.x * CDIM + lane];
        float a0 = __uint_as_float(v0 << 16), b0 = __uint_as_float(v0 & 0xffff0000u);
        float a1 = __uint_as_float(v1 << 16), b1 = __uint_as_float(v1 & 0xffff0000u);
        float a2 = __uint_as_float(v2 << 16), b2 = __uint_as_float(v2 & 0xffff0000u);
        float a3 = __uint_as_float(v3 << 16), b3 = __uint_as_float(v3 & 0xffff0000u);
        acc += a0 + __int_as_float(e0.y) * (b0 - a0);  // (1-u)h0 + u h1
        acc += a1 + __int_as_float(e1.y) * (b1 - a1);
        acc += a2 + __int_as_float(e2.y) * (b2 - a2);
        acc += a3 + __int_as_float(e3.y) * (b3 - a3);
    }
    for (; j < end; ++j) {
        int2 e = em[j];
        unsigned v = h01[(size_t)e.x * CDIM + lane];
        float a = __uint_as_float(v << 16), b = __uint_as_float(v & 0xffff0000u);
        acc += a + __int_as_float(e.y) * (b - a);
    }
    float d = fmaxf((float)(end - start), 1.0f);
    size_t o = (size_t)n * CDIM + lane;
    out[o] = acc / d + lin[o];
}

extern "C" void kernel_launch(void* const* d_in, const int* in_sizes, int n_in,
                              void* d_out, int out_size, void* d_ws, size_t ws_size,
                              hipStream_t stream) {
    const float* x = (const float*)d_in[0];
    const int* edge_index = (const int*)d_in[1];
    const float* edge_attr = (const float*)d_in[2];
    const float* w1 = (const float*)d_in[3];
    const float* root1 = (const float*)d_in[4];
    const float* b1 = (const float*)d_in[5];
    const float* w2 = (const float*)d_in[6];
    const float* root2 = (const float*)d_in[7];
    const float* b2 = (const float*)d_in[8];

    int n_nodes = in_sizes[0] / CDIM;
    int n_edges = in_sizes[2];
    const int* src = edge_index;
    const int* dst = edge_index + n_edges;

    size_t F = (size_t)n_nodes * CDIM;
    unsigned* h01 = (unsigned*)d_ws;            // F u32 (bf16 pair)
    float* lin = (float*)(h01 + F);             // F floats
    int2* em = (int2*)(lin + F);                // E int2 (src, u)
    int* cnt = (int*)(em + n_edges);
    int* row_start = cnt + n_nodes;             // n+1
    int* cursor = row_start + n_nodes + 1;
    int* blk_sum = cursor + n_nodes;
    float* out = (float*)d_out;

    int gN = (n_nodes + 255) / 256;
    int gE = (n_edges + 255) / 256;
    int gA = (n_nodes + 3) / 4;
    int nb = (n_nodes + SCAN_B - 1) / SCAN_B;   // 98 for 100k, fits k_scan2's 256

    // ---- build dst-CSR (shared by both layers) ----
    k_zero<<<256, 256, 0, stream>>>(cnt, (size_t)n_nodes);
    k_hist<<<gE, 256, 0, stream>>>(dst, cnt, n_edges);
    k_scan1<<<nb, 256, 0, stream>>>(cnt, blk_sum, n_nodes);
    k_scan2<<<1, 256, 0, stream>>>(blk_sum, row_start, nb, n_nodes);
    k_scan3<<<nb, 256, 0, stream>>>(cnt, blk_sum, row_start, cursor, n_nodes);
    k_scatter<<<gE, 256, 0, stream>>>(src, dst, edge_attr, cursor, em, n_edges);

    // ---- layer 1 ----
    k_gemm3<<<gN, 256, 0, stream>>>(x, w1, w1 + CDIM * CDIM, root1, b1, h01, lin, n_nodes);
    k_agg<<<gA, 256, 0, stream>>>(h01, em, row_start, lin, lin, n_nodes);  // lin <- layer-1 out

    // ---- layer 2 ----
    k_gemm3<<<gN, 256, 0, stream>>>(lin, w2, w2 + CDIM * CDIM, root2, b2, h01, out, n_nodes);
    k_agg<<<gA, 256, 0, stream>>>(h01, em, row_start, out, out, n_nodes);
}

// Round 6
// 429.691 us; speedup vs baseline: 7.1458x; 1.4221x over previous
//
#include <hip/hip_runtime.h>

#define CDIM 64

typedef __attribute__((ext_vector_type(8))) short bf16x8;
typedef __attribute__((ext_vector_type(4))) float f32x4;

// round-to-nearest-even fp32 -> bf16 (as short)
__device__ __forceinline__ short bf16r(float f) {
    unsigned a = __float_as_uint(f);
    a = (a + 0x7fffu + ((a >> 16) & 1u)) >> 16;
    return (short)a;
}
// pack two fp32 as bf16 pair: lo bits[15:0], hi bits[31:16]
__device__ __forceinline__ unsigned bfpack(float lo, float hi) {
    unsigned a = __float_as_uint(lo);
    a = (a + 0x7fffu + ((a >> 16) & 1u)) >> 16;
    unsigned b = __float_as_uint(hi);
    b = (b + 0x7fffu + ((b >> 16) & 1u)) & 0xffff0000u;
    return a | b;
}

// --- MFMA 3-GEMM: block = 64 nodes (4 waves x 16); W^T staged in LDS bf16 ---
// m92-verified layout: A[m=lane&15][k=quad*8+j]; B from Bt[n=lane&15][k=quad*8+j];
// D: col=lane&15 (n), row=quad*4+reg (m).
__global__ __launch_bounds__(256) void k_gemm3(const float* __restrict__ x,
                                               const float* __restrict__ w0,
                                               const float* __restrict__ w1,
                                               const float* __restrict__ root,
                                               const float* __restrict__ bias,
                                               unsigned* __restrict__ h01,
                                               float* __restrict__ lin,
                                               int n_nodes) {
    // Wt[mat][n][k], k padded 64->72 so rows are 144 B (16B-aligned b128 reads)
    __shared__ __align__(16) short wt[3][64][72];
    const float* ws[3] = {w0, w1, root};
#pragma unroll
    for (int m = 0; m < 3; ++m) {
        const float* w = ws[m];
        for (int i = threadIdx.x; i < 4096; i += 256) {
            int k = i >> 6, n = i & 63;      // w row-major [k][n]
            wt[m][n][k] = bf16r(w[i]);
        }
    }
    __syncthreads();

    int wave = threadIdx.x >> 6;
    int lane = threadIdx.x & 63;
    int quad = lane >> 4;
    int m16 = lane & 15;
    int node0 = blockIdx.x * 64 + wave * 16;

    // A-frags: 16 nodes x 64 k, two k-halves
    bf16x8 afrag[2];
    int arow = node0 + m16;
    bool rowok = arow < n_nodes;
    const float* xp = x + (size_t)arow * CDIM + quad * 8;
#pragma unroll
    for (int kf = 0; kf < 2; ++kf) {
        float4 lo = {0.f, 0.f, 0.f, 0.f}, hi = {0.f, 0.f, 0.f, 0.f};
        if (rowok) {
            lo = *(const float4*)(xp + kf * 32);
            hi = *(const float4*)(xp + kf * 32 + 4);
        }
        bf16x8 a;
        a[0] = bf16r(lo.x); a[1] = bf16r(lo.y); a[2] = bf16r(lo.z); a[3] = bf16r(lo.w);
        a[4] = bf16r(hi.x); a[5] = bf16r(hi.y); a[6] = bf16r(hi.z); a[7] = bf16r(hi.w);
        afrag[kf] = a;
    }

#pragma unroll
    for (int nt = 0; nt < 4; ++nt) {
        f32x4 acc0 = {0.f, 0.f, 0.f, 0.f};
        f32x4 acc1 = {0.f, 0.f, 0.f, 0.f};
        f32x4 accR = {0.f, 0.f, 0.f, 0.f};
#pragma unroll
        for (int kf = 0; kf < 2; ++kf) {
            const short* base0 = &wt[0][nt * 16 + m16][kf * 32 + quad * 8];
            const short* base1 = &wt[1][nt * 16 + m16][kf * 32 + quad * 8];
            const short* baseR = &wt[2][nt * 16 + m16][kf * 32 + quad * 8];
            bf16x8 b0 = *(const bf16x8*)base0;
            bf16x8 b1 = *(const bf16x8*)base1;
            bf16x8 bR = *(const bf16x8*)baseR;
            acc0 = __builtin_amdgcn_mfma_f32_16x16x32_bf16(afrag[kf], b0, acc0, 0, 0, 0);
            acc1 = __builtin_amdgcn_mfma_f32_16x16x32_bf16(afrag[kf], b1, acc1, 0, 0, 0);
            accR = __builtin_amdgcn_mfma_f32_16x16x32_bf16(afrag[kf], bR, accR, 0, 0, 0);
        }
        float bcol = bias[nt * 16 + m16];
#pragma unroll
        for (int r = 0; r < 4; ++r) {
            int node = node0 + quad * 4 + r;
            if (node < n_nodes) {
                size_t off = (size_t)node * CDIM + nt * 16 + m16;
                h01[off] = bfpack(acc0[r], acc1[r]);
                lin[off] = accR[r] + bcol;
            }
        }
    }
}

// --- zero-fill ---
__global__ __launch_bounds__(256) void k_zero(int* __restrict__ p, size_t n) {
    size_t t = (size_t)blockIdx.x * 256 + threadIdx.x;
    size_t stride = (size_t)gridDim.x * 256;
    for (size_t i = t; i < n; i += stride) p[i] = 0;
}

// --- histogram of dst ---
__global__ __launch_bounds__(256) void k_hist(const int* __restrict__ dst,
                                              int* __restrict__ cnt, int n_edges) {
    int e = blockIdx.x * 256 + threadIdx.x;
    if (e >= n_edges) return;
    atomicAdd(&cnt[dst[e]], 1);
}

// ===== two-level scan: 1024 elements per block =====
#define SCAN_B 1024

__global__ __launch_bounds__(256) void k_scan1(const int* __restrict__ cnt,
                                               int* __restrict__ blk_sum, int n) {
    __shared__ int sm[256];
    int tid = threadIdx.x;
    int base = blockIdx.x * SCAN_B + tid * 4;
    int s = 0;
#pragma unroll
    for (int i = 0; i < 4; ++i) s += (base + i < n) ? cnt[base + i] : 0;
    sm[tid] = s;
    __syncthreads();
    for (int off = 128; off > 0; off >>= 1) {
        if (tid < off) sm[tid] += sm[tid + off];
        __syncthreads();
    }
    if (tid == 0) blk_sum[blockIdx.x] = sm[0];
}

__global__ __launch_bounds__(256) void k_scan2(int* __restrict__ blk_sum,
                                               int* __restrict__ row_start,
                                               int nb, int n) {
    __shared__ int sm[256];
    int tid = threadIdx.x;
    int v = (tid < nb) ? blk_sum[tid] : 0;
    sm[tid] = v;
    __syncthreads();
    for (int off = 1; off < 256; off <<= 1) {
        int t = (tid >= off) ? sm[tid - off] : 0;
        __syncthreads();
        sm[tid] += t;
        __syncthreads();
    }
    if (tid < nb) blk_sum[tid] = sm[tid] - v;  // exclusive
    if (tid == 255) row_start[n] = sm[255];    // grand total
}

__global__ __launch_bounds__(256) void k_scan3(const int* __restrict__ cnt,
                                               const int* __restrict__ blk_off,
                                               int* __restrict__ row_start,
                                               int* __restrict__ cursor, int n) {
    __shared__ int sm[256];
    int tid = threadIdx.x;
    int base = blockIdx.x * SCAN_B + tid * 4;
    int v[4];
    int s = 0;
#pragma unroll
    for (int i = 0; i < 4; ++i) {
        v[i] = (base + i < n) ? cnt[base + i] : 0;
        s += v[i];
    }
    sm[tid] = s;
    __syncthreads();
    for (int off = 1; off < 256; off <<= 1) {
        int t = (tid >= off) ? sm[tid - off] : 0;
        __syncthreads();
        sm[tid] += t;
        __syncthreads();
    }
    int run = sm[tid] - s + blk_off[blockIdx.x];
#pragma unroll
    for (int i = 0; i < 4; ++i) {
        if (base + i < n) {
            row_start[base + i] = run;
            cursor[base + i] = run;
        }
        run += v[i];
    }
}

// --- bucketed scatter: bucket = blockIdx&7 (XCD round-robin heuristic) ---
// Each bucket owns a ~1.6 MB dst-sorted window -> write lines fill in one
// XCD's L2 before writeback. Correct regardless of actual block->XCD mapping.
__global__ __launch_bounds__(256) void k_scatter(const int* __restrict__ src,
                                                 const int* __restrict__ dst,
                                                 const float* __restrict__ u,
                                                 int* __restrict__ cursor,
                                                 int2* __restrict__ em,
                                                 int n_edges, int nodes_per_bucket) {
    int bucket = blockIdx.x & 7;
    int chunk = blockIdx.x >> 3;
    int nchunks = gridDim.x >> 3;
    int per = (n_edges + nchunks - 1) / nchunks;
    int e0 = chunk * per;
    int e1 = min(e0 + per, n_edges);
    int lo = bucket * nodes_per_bucket;
    int hi = lo + nodes_per_bucket;
    for (int e = e0 + threadIdx.x; e < e1; e += 256) {
        int d = dst[e];
        if (d >= lo && d < hi) {
            int p = atomicAdd(&cursor[d], 1);
            em[p] = make_int2(src[e], __float_as_int(u[e]));
        }
    }
}

// --- aggregate: one wave per node, lane = channel; packed bf16 h01, fused epilogue ---
__global__ __launch_bounds__(256) void k_agg(const unsigned* __restrict__ h01,
                                             const int2* __restrict__ em,
                                             const int* __restrict__ row_start,
                                             const float* __restrict__ lin,
                                             float* __restrict__ out, int n_nodes) {
    int wave = threadIdx.x >> 6;
    int lane = threadIdx.x & 63;
    int n = blockIdx.x * 4 + wave;
    if (n >= n_nodes) return;
    int start = row_start[n];
    int end = row_start[n + 1];
    float acc = 0.0f;
    int j = start;
    for (; j + 8 <= end; j += 8) {
        int2 e[8];
        unsigned v[8];
#pragma unroll
        for (int i = 0; i < 8; ++i) e[i] = em[j + i];
#pragma unroll
        for (int i = 0; i < 8; ++i) v[i] = h01[(size_t)e[i].x * CDIM + lane];
#pragma unroll
        for (int i = 0; i < 8; ++i) {
            float a = __uint_as_float(v[i] << 16);
            float b = __uint_as_float(v[i] & 0xffff0000u);
            acc += a + __int_as_float(e[i].y) * (b - a);   // (1-u)h0 + u h1
        }
    }
    for (; j < end; ++j) {
        int2 e = em[j];
        unsigned v = h01[(size_t)e.x * CDIM + lane];
        float a = __uint_as_float(v << 16), b = __uint_as_float(v & 0xffff0000u);
        acc += a + __int_as_float(e.y) * (b - a);
    }
    float d = fmaxf((float)(end - start), 1.0f);
    size_t o = (size_t)n * CDIM + lane;
    out[o] = acc / d + lin[o];
}

extern "C" void kernel_launch(void* const* d_in, const int* in_sizes, int n_in,
                              void* d_out, int out_size, void* d_ws, size_t ws_size,
                              hipStream_t stream) {
    const float* x = (const float*)d_in[0];
    const int* edge_index = (const int*)d_in[1];
    const float* edge_attr = (const float*)d_in[2];
    const float* w1 = (const float*)d_in[3];
    const float* root1 = (const float*)d_in[4];
    const float* b1 = (const float*)d_in[5];
    const float* w2 = (const float*)d_in[6];
    const float* root2 = (const float*)d_in[7];
    const float* b2 = (const float*)d_in[8];

    int n_nodes = in_sizes[0] / CDIM;
    int n_edges = in_sizes[2];
    const int* src = edge_index;
    const int* dst = edge_index + n_edges;

    size_t F = (size_t)n_nodes * CDIM;
    unsigned* h01 = (unsigned*)d_ws;            // F u32 (bf16 pair)
    float* lin = (float*)(h01 + F);             // F floats
    int2* em = (int2*)(lin + F);                // E int2 (src, u)
    int* cnt = (int*)(em + n_edges);
    int* row_start = cnt + n_nodes;             // n+1
    int* cursor = row_start + n_nodes + 1;
    int* blk_sum = cursor + n_nodes;
    float* out = (float*)d_out;

    int gB = (n_nodes + 63) / 64;               // 64 nodes per gemm block
    int gE = (n_edges + 255) / 256;
    int gA = (n_nodes + 3) / 4;
    int nb = (n_nodes + SCAN_B - 1) / SCAN_B;   // 98 for 100k, fits k_scan2's 256
    int npb = (n_nodes + 7) / 8;                // nodes per scatter bucket

    // ---- build dst-CSR (shared by both layers) ----
    k_zero<<<256, 256, 0, stream>>>(cnt, (size_t)n_nodes);
    k_hist<<<gE, 256, 0, stream>>>(dst, cnt, n_edges);
    k_scan1<<<nb, 256, 0, stream>>>(cnt, blk_sum, n_nodes);
    k_scan2<<<1, 256, 0, stream>>>(blk_sum, row_start, nb, n_nodes);
    k_scan3<<<nb, 256, 0, stream>>>(cnt, blk_sum, row_start, cursor, n_nodes);
    k_scatter<<<8 * 128, 256, 0, stream>>>(src, dst, edge_attr, cursor, em, n_edges, npb);

    // ---- layer 1 ----
    k_gemm3<<<gB, 256, 0, stream>>>(x, w1, w1 + CDIM * CDIM, root1, b1, h01, lin, n_nodes);
    k_agg<<<gA, 256, 0, stream>>>(h01, em, row_start, lin, lin, n_nodes);  // lin <- layer-1 out

    // ---- layer 2 ----
    k_gemm3<<<gB, 256, 0, stream>>>(lin, w2, w2 + CDIM * CDIM, root2, b2, h01, out, n_nodes);
    k_agg<<<gA, 256, 0, stream>>>(h01, em, row_start, out, out, n_nodes);
}